// Round 10
// baseline (149.980 us; speedup 1.0000x reference)
//
#include <hip/hip_runtime.h>
#include <hip/hip_bf16.h>
#include <hip/hip_fp8.h>

typedef __bf16 bf16_t;
typedef __bf16 bf16x8 __attribute__((ext_vector_type(8)));
typedef float  f32x4  __attribute__((ext_vector_type(4)));
typedef long   i64_t;

#define MFMA16(A,B,C) __builtin_amdgcn_mfma_f32_16x16x32_bf16((A),(B),(C),0,0,0)
#define MFMA8(A,B,C)  __builtin_amdgcn_mfma_f32_16x16x32_fp8_fp8((A),(B),(C),0,0,0)
// PV: A = P in e5m2 (bf8), B = V/ones in e4m3 (fp8)
#define MFMA85(A,B,C) __builtin_amdgcn_mfma_f32_16x16x32_bf8_fp8((A),(B),(C),0,0,0)

constexpr int Bn = 2, Cc = 128, Hh = 64, Wd = 64;
constexpr int N  = Hh * Wd;      // 4096 tokens per batch
constexpr int T  = Bn * N;       // 8192 tokens total
constexpr int D  = 2 * Cc;       // 256 = [real | imag] channels
constexpr int NSP = 4;           // key splits (r8 best-total config)
constexpr float EPS = 1e-5f;
constexpr float SCL = 0.08838834764831845f * 1.4426950408889634f; // C^-0.5 * log2(e)
// P stored e5m2 with PSH=9 (r8-proven): e5m2's 32-octave range holds the
// fixed-max P spread; 2^-PSH cancels exactly in k_comb normalization.
constexpr float PSH = 9.0f;

// bf16 fragment-ordered 64-row x 256-ch tile (32 KB), 1KB frags (k_qkv inputs)
__device__ __forceinline__ int tfrag(int row, int ch) {
    return (((ch >> 5) * 4 + (row >> 4)) << 10) +
           ((((ch >> 3) & 3) * 16 + (row & 15)) << 4) + (ch & 7) * 2;
}

__device__ __forceinline__ void gl16(const void* g, void* l) {
    __builtin_amdgcn_global_load_lds(
        (const __attribute__((address_space(1))) void*)g,
        (__attribute__((address_space(3))) void*)l, 16, 0, 0);
}

// ---- kernel 1: fused BN partial stats (blocks 0..511) + weight prep (512..1279)
__global__ void k_pre(const float* __restrict__ x, float4* __restrict__ part,
                      const float* __restrict__ wq, const float* __restrict__ wk,
                      const float* __restrict__ wv, const float* __restrict__ bq,
                      const float* __restrict__ bk, const float* __restrict__ bv,
                      char* __restrict__ Wg, float* __restrict__ bt) {
    int tid = threadIdx.x;
    if (blockIdx.x < 512) {
        int bid = blockIdx.x;            // q*128 + c
        int q = bid >> 7, c = bid & 127;
        float sr = 0.f, si = 0.f, qr = 0.f, qi = 0.f;
        for (int b = 0; b < Bn; ++b) {
            const float4* p = (const float4*)((const float2*)x +
                              (size_t)(b * Cc + c) * N + q * 1024);
            for (int i = tid; i < 512; i += 256) {       // float4 = 2 complex
                float4 v = p[i];
                sr += v.x + v.z; si += v.y + v.w;
                qr += v.x * v.x + v.z * v.z; qi += v.y * v.y + v.w * v.w;
            }
        }
        #pragma unroll
        for (int d = 32; d >= 1; d >>= 1) {
            sr += __shfl_xor(sr, d); si += __shfl_xor(si, d);
            qr += __shfl_xor(qr, d); qi += __shfl_xor(qi, d);
        }
        __shared__ float red[4][4];
        int w = tid >> 6;
        if ((tid & 63) == 0) { red[w][0] = sr; red[w][1] = si; red[w][2] = qr; red[w][3] = qi; }
        __syncthreads();
        if (tid == 0) {
            part[c * 4 + q] = make_float4(red[0][0] + red[1][0] + red[2][0] + red[3][0],
                                          red[0][1] + red[1][1] + red[2][1] + red[3][1],
                                          red[0][2] + red[1][2] + red[2][2] + red[3][2],
                                          red[0][3] + red[1][3] + red[2][3] + red[3][3]);
        }
    } else {
        int o = blockIdx.x - 512;        // 768 = [Qr Qi Kr Ki Vr Vi] x128
        int k = tid;
        int proj = o >> 8, oc = o & 255;
        const float* wsrc = proj == 0 ? wq : (proj == 1 ? wk : wv);
        const float* bsrc = proj == 0 ? bq : (proj == 1 ? bk : bv);
        int co = oc >> 7, oo = oc & 127;
        int c = k & 127, kc = k >> 7;
        float val;
        if (co == 0) val = (kc == 0) ? wsrc[(oo * 128 + c) * 2 + 0] : -wsrc[(oo * 128 + c) * 2 + 1];
        else         val = (kc == 0) ? wsrc[(oo * 128 + c) * 2 + 1] :  wsrc[(oo * 128 + c) * 2 + 0];
        int tile = o >> 6, row = o & 63;
        *(bf16_t*)(Wg + (size_t)tile * 32768 + tfrag(row, k)) = (bf16_t)val;
        if (k == 0) bt[o] = bsrc[oo * 2 + co];
    }
}

// ---- kernel 2: finalize stats + normalize -> bf16 frag tiles XNg only ------
__global__ void k_norm(const float* __restrict__ x, const float4* __restrict__ part,
                       const float* __restrict__ bn_w, const float* __restrict__ bn_b,
                       char* __restrict__ XNg) {
    __shared__ float4 ssl[128];
    __shared__ __align__(16) char Tsh[32768];
    int blk = blockIdx.x;        // 128 token tiles
    int b = blk >> 6, hw0 = (blk & 63) * 64;
    int tid = threadIdx.x;
    if (tid < 128) {
        float4 p0 = part[tid * 4 + 0], p1 = part[tid * 4 + 1];
        float4 p2 = part[tid * 4 + 2], p3 = part[tid * 4 + 3];
        float sr = p0.x + p1.x + p2.x + p3.x, si = p0.y + p1.y + p2.y + p3.y;
        float qr = p0.z + p1.z + p2.z + p3.z, qi = p0.w + p1.w + p2.w + p3.w;
        const float inv = 1.0f / (float)(Bn * N);
        float mr = sr * inv, mi = si * inv;
        float vr = qr * inv - mr * mr, vi = qi * inv - mi * mi;
        float scr = bn_w[tid * 2 + 0] * rsqrtf(vr + EPS);
        float sci = bn_w[tid * 2 + 1] * rsqrtf(vi + EPS);
        ssl[tid] = make_float4(scr, bn_b[tid * 2 + 0] - mr * scr,
                               sci, bn_b[tid * 2 + 1] - mi * sci);
    }
    __syncthreads();
    const float4* xin4 = (const float4*)x;
    #pragma unroll
    for (int it = 0; it < 16; ++it) {
        int idx = it * 256 + tid;        // 4096 = 128c x 32 float4 (2 tokens)
        int c = idx >> 5, h2 = (idx & 31) * 2;
        size_t gi = ((size_t)(b * Cc + c) * N + hw0 + h2) >> 1;  // float4 idx
        float4 v = xin4[gi];
        float4 s = ssl[c];
        *(bf16_t*)(Tsh + tfrag(h2, c))           = (bf16_t)(v.x * s.x + s.y);
        *(bf16_t*)(Tsh + tfrag(h2, c + 128))     = (bf16_t)(v.y * s.z + s.w);
        *(bf16_t*)(Tsh + tfrag(h2 + 1, c))       = (bf16_t)(v.z * s.x + s.y);
        *(bf16_t*)(Tsh + tfrag(h2 + 1, c + 128)) = (bf16_t)(v.w * s.z + s.w);
    }
    __syncthreads();
    #pragma unroll
    for (int it = 0; it < 8; ++it) {
        int idx = it * 256 + tid;
        *(uint4*)(XNg + (size_t)blk * 32768 + idx * 16) = *(const uint4*)(Tsh + idx * 16);
    }
}

// ---- kernel 3: QKV GEMM [8192x256]@[256x768] bf16; fp8 frag images out ----
// r10: epilogue restaged through LDS -> one coalesced dwordx4 store/thread
// (was 16 scattered single-byte global stores/thread).
__global__ __launch_bounds__(256) void k_qkv(const char* __restrict__ XNg,
        const char* __restrict__ Wg, const float* __restrict__ bt,
        char* __restrict__ Qg, char* __restrict__ Kg, char* __restrict__ Vg) {
    __shared__ __align__(16) char Xsh[32768];
    __shared__ __align__(16) char Wsh[32768];
    int mx = blockIdx.x, ny = blockIdx.y;   // 128 x 12
    int tid = threadIdx.x;
    int w = tid >> 6, lane = tid & 63, n15 = lane & 15, quad = lane >> 4;
    const char* xs = XNg + (size_t)mx * 32768;
    const char* wsp = Wg + (size_t)ny * 32768;
    #pragma unroll
    for (int i = 0; i < 8; ++i) {
        int off = (w * 8 + i) * 1024 + lane * 16;
        gl16(xs + off, Xsh + off);
        gl16(wsp + off, Wsh + off);
    }
    __syncthreads();
    f32x4 acc[4] = {};
    #pragma unroll
    for (int ks = 0; ks < 8; ++ks) {
        bf16x8 a = *(const bf16x8*)(Xsh + (ks * 4 + w) * 1024 + lane * 16);
        #pragma unroll
        for (int t = 0; t < 4; ++t) {
            bf16x8 bw = *(const bf16x8*)(Wsh + (ks * 4 + t) * 1024 + lane * 16);
            acc[t] = MFMA16(a, bw, acc[t]);
        }
    }
    int proj = ny >> 2;            // 0=Q 1=K 2=V
    int jb = (ny & 3) * 64;
    // --- restage epilogue: build the 4KB fp8 frag-image slice in LDS ---
    __syncthreads();               // all MFMA reads of Xsh done
    char* Osh = Xsh;               // reuse 4KB
    #pragma unroll
    for (int t = 0; t < 4; ++t) {
        float bias = bt[ny * 64 + t * 16 + n15];
        unsigned w01 = (unsigned)__builtin_amdgcn_cvt_pk_fp8_f32(
            acc[t][0] + bias, acc[t][1] + bias, 0, false);
        unsigned w23 = (unsigned)__builtin_amdgcn_cvt_pk_fp8_f32(
            acc[t][2] + bias, acc[t][3] + bias, 0, false);
        unsigned char vb[4] = {(unsigned char)(w01 & 0xff), (unsigned char)((w01 >> 8) & 0xff),
                               (unsigned char)(w23 & 0xff), (unsigned char)((w23 >> 8) & 0xff)};
        #pragma unroll
        for (int r = 0; r < 4; ++r) {
            if (proj < 2) {
                // Q/K row-major frag: lf=(ch_hi)*4+rowgrp; lif=((j>>3)&3)*16+row&15
                int lf  = (t >> 1) * 4 + w;
                int lif = (((2 * t + (n15 >> 3)) & 3) << 4) + quad * 4 + r;
                Osh[lf * 512 + lif * 8 + (n15 & 7)] = vb[r];
            } else {
                // V key-major frag: lf=(key>>5)*4+t; lif=((key>>3)&3)*16+ch&15
                int key = w * 16 + quad * 4 + r;
                int lf  = (w >> 1) * 4 + t;
                int lif = (((key >> 3) & 3) << 4) + n15;
                Osh[lf * 512 + lif * 8 + (key & 7)] = vb[r];
            }
        }
    }
    __syncthreads();
    // --- coalesced copy-out: 256 threads x 16B = 4KB slice ---
    {
        int lf = tid >> 5, sub = (tid & 31) * 16;
        size_t tile = (proj == 0) ? (size_t)mx
                                  : (size_t)((mx >> 6) * 64 + (mx & 63));
        int gfrag = (proj < 2) ? ((jb >> 5) * 4 + lf)
                               : ((lf >> 2) * 16 + (jb >> 4) + (lf & 3));
        char* dst = (proj == 0 ? Qg : (proj == 1 ? Kg : Vg));
        *(uint4*)(dst + tile * 16384 + (size_t)gfrag * 512 + sub) =
            *(const uint4*)(Osh + tid * 16);
    }
}

// ---- kernel 4: flash attention, FIXED-MAX softmax, fp8 Q/K/V + e5m2 P.
// r10 = r9 body (HW packed cvt) at NSP=4 (r8's best-total config).
__global__ __launch_bounds__(256, 4) void k_attn(const char* __restrict__ Qg,
        const char* __restrict__ Kg, const char* __restrict__ Vg,
        bf16_t* __restrict__ Opb, float* __restrict__ Lp) {
    __shared__ __align__(16) char Ksh[16384];   // K tile: 64 keys x 256 ch fp8
    __shared__ __align__(16) char Vsh[16384];   // V tile: 256 ch x 64 keys fp8
    __shared__ __align__(16) char Psh[4096];    // P: 64 rows x 64 keys e5m2
    int bid = blockIdx.x;               // 512 = grp(8 = b*4+sp) x qt(64)
    int grp = bid & 7, qt = bid >> 3;   // grp -> XCD affinity
    int sp = grp & 3, b = grp >> 2;
    int tid = threadIdx.x;
    int w = tid >> 6, lane = tid & 63, n15 = lane & 15, quad = lane >> 4;
    int r = w >> 1, h = w & 1;

    const i64_t ONES = 0x3838383838383838L;   // e4m3 1.0 in all 8 bytes

    // Q fragments: rows qt*64 + r*32 + g*16, resident (32 VGPRs)
    i64_t qf[2][8];
    const char* qb = Qg + (size_t)(b * 64 + qt) * 16384;
    #pragma unroll
    for (int g = 0; g < 2; ++g)
        #pragma unroll
        for (int ks = 0; ks < 8; ++ks)
            qf[g][ks] = *(const i64_t*)(qb + ((ks * 4 + r * 2 + g) << 9) + lane * 8);

    f32x4 o[2][8] = {};                 // 32 rows x 128 ch accumulator
    f32x4 l_[2] = {};                   // row sums via ones-channel MFMA

    for (int kt = 0; kt < 16; ++kt) {   // 16 tiles of 64 keys (split = 1024)
        size_t tb = (size_t)(b * 64 + sp * 16 + kt) * 16384;
        __syncthreads();                              // (A) prev iter consumed
        #pragma unroll
        for (int i = 0; i < 4; ++i) {
            int off = (w * 4 + i) * 1024 + lane * 16;
            gl16(Kg + tb + off, Ksh + off);
            gl16(Vg + tb + off, Vsh + off);
        }
        __syncthreads();                              // (B) staging landed

        // QK^T: 32 rows x 32 keys (key half h) over 256 ch
        f32x4 s[2][2] = {};
        #pragma unroll
        for (int ks = 0; ks < 8; ++ks) {
            #pragma unroll
            for (int c = 0; c < 2; ++c) {
                i64_t kf = *(const i64_t*)(Ksh + ((ks * 4 + h * 2 + c) << 9) + lane * 8);
                s[0][c] = MFMA8(qf[0][ks], kf, s[0][c]);
                s[1][c] = MFMA8(qf[1][ks], kf, s[1][c]);
            }
        }
        // P' = exp2(s*SCL - PSH), e5m2 via HW packed cvt (2 vals/instr)
        #pragma unroll
        for (int g = 0; g < 2; ++g)
            #pragma unroll
            for (int c = 0; c < 2; ++c) {
                float p0 = __builtin_amdgcn_exp2f(s[g][c][0] * SCL - PSH);
                float p1 = __builtin_amdgcn_exp2f(s[g][c][1] * SCL - PSH);
                float p2 = __builtin_amdgcn_exp2f(s[g][c][2] * SCL - PSH);
                float p3 = __builtin_amdgcn_exp2f(s[g][c][3] * SCL - PSH);
                unsigned w01 = (unsigned)__builtin_amdgcn_cvt_pk_bf8_f32(p0, p1, 0, false);
                unsigned w23 = (unsigned)__builtin_amdgcn_cvt_pk_bf8_f32(p2, p3, 0, false);
                char* pb = Psh + ((h * 4 + r * 2 + g) << 9) +
                           (((c * 2 + (n15 >> 3)) * 16 + quad * 4) << 3) + (n15 & 7);
                pb[0]  = (unsigned char)(w01 & 0xff);
                pb[8]  = (unsigned char)((w01 >> 8) & 0xff);
                pb[16] = (unsigned char)(w23 & 0xff);
                pb[24] = (unsigned char)((w23 >> 8) & 0xff);
            }
        __syncthreads();                              // (C) P visible

        // PV (bf8 x fp8): rows r*32.. x ch-half h over 64 keys; + ones -> l
        #pragma unroll
        for (int k2 = 0; k2 < 2; ++k2) {
            i64_t pa0 = *(const i64_t*)(Psh + ((k2 * 4 + r * 2 + 0) << 9) + lane * 8);
            i64_t pa1 = *(const i64_t*)(Psh + ((k2 * 4 + r * 2 + 1) << 9) + lane * 8);
            l_[0] = MFMA85(pa0, ONES, l_[0]);
            l_[1] = MFMA85(pa1, ONES, l_[1]);
            #pragma unroll
            for (int ct = 0; ct < 8; ++ct) {
                i64_t vf = *(const i64_t*)(Vsh + ((k2 * 16 + h * 8 + ct) << 9) + lane * 8);
                o[0][ct] = MFMA85(pa0, vf, o[0][ct]);
                o[1][ct] = MFMA85(pa1, vf, o[1][ct]);
            }
        }
    }
    // epilogue: unnormalized O (bf16, carries 2^-PSH) + l for this split
    int tok0 = b * N + qt * 64 + r * 32;
    #pragma unroll
    for (int g = 0; g < 2; ++g) {
        #pragma unroll
        for (int ct = 0; ct < 8; ++ct)
            #pragma unroll
            for (int ri = 0; ri < 4; ++ri)
                Opb[((size_t)sp * T + tok0 + g * 16 + quad * 4 + ri) * D +
                    h * 128 + ct * 16 + n15] = (bf16_t)o[g][ct][ri];
        if (h == 0 && n15 == 0) {
            #pragma unroll
            for (int ri = 0; ri < 4; ++ri)
                Lp[sp * T + tok0 + g * 16 + quad * 4 + ri] = l_[g][ri];
        }
    }
}

// ---- kernel 5: combine splits + normalize + recompute xn + residual --------
// r10: 512 blocks x 16 tokens (was 256 x 32) -> 2 blocks/CU phase overlap.
__global__ void k_comb(const bf16_t* __restrict__ Opb, const float* __restrict__ Lp,
                       const float4* __restrict__ part, const float* __restrict__ bn_w,
                       const float* __restrict__ bn_b, const float* __restrict__ x,
                       const float* __restrict__ gamma, float* __restrict__ out) {
    __shared__ float4 ssl[128];
    __shared__ float wts[16];
    __shared__ float Ot[256 * 17];
    int blk = blockIdx.x;                // 512 blocks x 16 tokens
    int b = blk >> 8, hw0 = (blk & 255) * 16;
    int tok0 = b * N + hw0;
    int tid = threadIdx.x;
    if (tid < 128) {
        float4 p0 = part[tid * 4 + 0], p1 = part[tid * 4 + 1];
        float4 p2 = part[tid * 4 + 2], p3 = part[tid * 4 + 3];
        float sr = p0.x + p1.x + p2.x + p3.x, si = p0.y + p1.y + p2.y + p3.y;
        float qr = p0.z + p1.z + p2.z + p3.z, qi = p0.w + p1.w + p2.w + p3.w;
        const float inv = 1.0f / (float)(Bn * N);
        float mr = sr * inv, mi = si * inv;
        float vr = qr * inv - mr * mr, vi = qi * inv - mi * mi;
        float scr = bn_w[tid * 2 + 0] * rsqrtf(vr + EPS);
        float sci = bn_w[tid * 2 + 1] * rsqrtf(vi + EPS);
        ssl[tid] = make_float4(scr, bn_b[tid * 2 + 0] - mr * scr,
                               sci, bn_b[tid * 2 + 1] - mi * sci);
    }
    if (tid < 16) {
        float Z = 0.f;
        #pragma unroll
        for (int s = 0; s < NSP; ++s) Z += Lp[s * T + tok0 + tid];
        wts[tid] = gamma[0] / Z;
    }
    __syncthreads();
    #pragma unroll
    for (int i = 0; i < 2; ++i) {
        int idx = i * 256 + tid;         // 512 chunks of 8 ch (16tok x 32)
        int tk = idx >> 5, chunk = idx & 31;
        size_t base = (size_t)(tok0 + tk) * D + chunk * 8;
        float acc[8] = {};
        #pragma unroll
        for (int s = 0; s < NSP; ++s) {
            bf16x8 v = *(const bf16x8*)(Opb + (size_t)s * T * D + base);
            #pragma unroll
            for (int j = 0; j < 8; ++j) acc[j] += (float)v[j];
        }
        float ww = wts[tk];
        #pragma unroll
        for (int j = 0; j < 8; ++j) Ot[(chunk * 8 + j) * 17 + tk] = acc[j] * ww;
    }
    __syncthreads();
    const float2* xin = (const float2*)x;
    float2* xo = (float2*)out;
    #pragma unroll
    for (int i = 0; i < 8; ++i) {
        int linear = i * 256 + tid;      // 2048 = 128c x 16hw
        int c = linear >> 4, hwo = linear & 15;
        size_t idx = (size_t)(b * Cc + c) * N + hw0 + hwo;
        float2 v = xin[idx];
        float4 s = ssl[c];
        float2 res;
        res.x = v.x * s.x + s.y + Ot[c * 17 + hwo];
        res.y = v.y * s.z + s.w + Ot[(128 + c) * 17 + hwo];
        xo[idx] = res;
    }
}

extern "C" void kernel_launch(void* const* d_in, const int* in_sizes, int n_in,
                              void* d_out, int out_size, void* d_ws, size_t ws_size,
                              hipStream_t stream) {
    const float* x    = (const float*)d_in[0];
    const float* bn_w = (const float*)d_in[1];
    const float* bn_b = (const float*)d_in[2];
    const float* wq   = (const float*)d_in[3];
    const float* bq   = (const float*)d_in[4];
    const float* wk   = (const float*)d_in[5];
    const float* bk   = (const float*)d_in[6];
    const float* wv   = (const float*)d_in[7];
    const float* bv   = (const float*)d_in[8];
    const float* gam  = (const float*)d_in[9];
    float* out = (float*)d_out;

    char* ws = (char*)d_ws;
    size_t off = 0;
    auto alloc = [&](size_t bytes) -> void* {
        void* p = ws + off;
        off += (bytes + 255) & ~(size_t)255;
        return p;
    };
    float4* part = (float4*)alloc(512 * sizeof(float4));
    char*   XNg  = (char*)alloc((size_t)128 * 32768);
    char*   Wg   = (char*)alloc((size_t)12 * 32768);
    float*  bt   = (float*)alloc(768 * 4);
    char*   Qg   = (char*)alloc((size_t)128 * 16384);   // fp8 images
    char*   Kg   = (char*)alloc((size_t)128 * 16384);
    char*   Vg   = (char*)alloc((size_t)128 * 16384);
    bf16_t* Opb  = (bf16_t*)alloc((size_t)NSP * T * D * 2);
    float*  Lp   = (float*)alloc((size_t)NSP * T * 4);

    k_pre<<<1280, 256, 0, stream>>>(x, part, wq, wk, wv, bq, bk, bv, Wg, bt);
    k_norm<<<128, 256, 0, stream>>>(x, part, bn_w, bn_b, XNg);
    k_qkv<<<dim3(128, 12), 256, 0, stream>>>(XNg, Wg, bt, Qg, Kg, Vg);
    k_attn<<<512, 256, 0, stream>>>(Qg, Kg, Vg, Opb, Lp);
    k_comb<<<512, 256, 0, stream>>>(Opb, Lp, part, bn_w, bn_b, x, gam, out);
}

// Round 11
// 141.611 us; speedup vs baseline: 1.0591x; 1.0591x over previous
//
#include <hip/hip_runtime.h>
#include <hip/hip_bf16.h>
#include <hip/hip_fp8.h>

typedef __bf16 bf16_t;
typedef __bf16 bf16x8 __attribute__((ext_vector_type(8)));
typedef float  f32x4  __attribute__((ext_vector_type(4)));
typedef long   i64_t;

#define MFMA16(A,B,C) __builtin_amdgcn_mfma_f32_16x16x32_bf16((A),(B),(C),0,0,0)
#define MFMA8(A,B,C)  __builtin_amdgcn_mfma_f32_16x16x32_fp8_fp8((A),(B),(C),0,0,0)
// PV: A = P in e5m2 (bf8), B = V/ones in e4m3 (fp8)
#define MFMA85(A,B,C) __builtin_amdgcn_mfma_f32_16x16x32_bf8_fp8((A),(B),(C),0,0,0)

constexpr int Bn = 2, Cc = 128, Hh = 64, Wd = 64;
constexpr int N  = Hh * Wd;      // 4096 tokens per batch
constexpr int T  = Bn * N;       // 8192 tokens total
constexpr int D  = 2 * Cc;       // 256 = [real | imag] channels
constexpr int NSP = 4;           // key splits
constexpr float EPS = 1e-5f;
constexpr float SCL = 0.08838834764831845f * 1.4426950408889634f; // C^-0.5 * log2(e)
// P stored e5m2 with PSH=9 (r8-proven): e5m2's 32-octave range holds the
// fixed-max P spread; 2^-PSH cancels exactly in k_comb normalization.
constexpr float PSH = 9.0f;

// bf16 fragment-ordered 64-row x 256-ch tile (32 KB), 1KB frags (k_qkv inputs)
__device__ __forceinline__ int tfrag(int row, int ch) {
    return (((ch >> 5) * 4 + (row >> 4)) << 10) +
           ((((ch >> 3) & 3) * 16 + (row & 15)) << 4) + (ch & 7) * 2;
}

__device__ __forceinline__ void gl16(const void* g, void* l) {
    __builtin_amdgcn_global_load_lds(
        (const __attribute__((address_space(1))) void*)g,
        (__attribute__((address_space(3))) void*)l, 16, 0, 0);
}

// ---- kernel 1: fused BN partial stats (blocks 0..511) + weight prep (512..1279)
__global__ void k_pre(const float* __restrict__ x, float4* __restrict__ part,
                      const float* __restrict__ wq, const float* __restrict__ wk,
                      const float* __restrict__ wv, const float* __restrict__ bq,
                      const float* __restrict__ bk, const float* __restrict__ bv,
                      char* __restrict__ Wg, float* __restrict__ bt) {
    int tid = threadIdx.x;
    if (blockIdx.x < 512) {
        int bid = blockIdx.x;            // q*128 + c
        int q = bid >> 7, c = bid & 127;
        float sr = 0.f, si = 0.f, qr = 0.f, qi = 0.f;
        for (int b = 0; b < Bn; ++b) {
            const float4* p = (const float4*)((const float2*)x +
                              (size_t)(b * Cc + c) * N + q * 1024);
            for (int i = tid; i < 512; i += 256) {       // float4 = 2 complex
                float4 v = p[i];
                sr += v.x + v.z; si += v.y + v.w;
                qr += v.x * v.x + v.z * v.z; qi += v.y * v.y + v.w * v.w;
            }
        }
        #pragma unroll
        for (int d = 32; d >= 1; d >>= 1) {
            sr += __shfl_xor(sr, d); si += __shfl_xor(si, d);
            qr += __shfl_xor(qr, d); qi += __shfl_xor(qi, d);
        }
        __shared__ float red[4][4];
        int w = tid >> 6;
        if ((tid & 63) == 0) { red[w][0] = sr; red[w][1] = si; red[w][2] = qr; red[w][3] = qi; }
        __syncthreads();
        if (tid == 0) {
            part[c * 4 + q] = make_float4(red[0][0] + red[1][0] + red[2][0] + red[3][0],
                                          red[0][1] + red[1][1] + red[2][1] + red[3][1],
                                          red[0][2] + red[1][2] + red[2][2] + red[3][2],
                                          red[0][3] + red[1][3] + red[2][3] + red[3][3]);
        }
    } else {
        int o = blockIdx.x - 512;        // 768 = [Qr Qi Kr Ki Vr Vi] x128
        int k = tid;
        int proj = o >> 8, oc = o & 255;
        const float* wsrc = proj == 0 ? wq : (proj == 1 ? wk : wv);
        const float* bsrc = proj == 0 ? bq : (proj == 1 ? bk : bv);
        int co = oc >> 7, oo = oc & 127;
        int c = k & 127, kc = k >> 7;
        float val;
        if (co == 0) val = (kc == 0) ? wsrc[(oo * 128 + c) * 2 + 0] : -wsrc[(oo * 128 + c) * 2 + 1];
        else         val = (kc == 0) ? wsrc[(oo * 128 + c) * 2 + 1] :  wsrc[(oo * 128 + c) * 2 + 0];
        int tile = o >> 6, row = o & 63;
        *(bf16_t*)(Wg + (size_t)tile * 32768 + tfrag(row, k)) = (bf16_t)val;
        if (k == 0) bt[o] = bsrc[oo * 2 + co];
    }
}

// ---- kernel 2: finalize stats + normalize -> bf16 frag tiles XNg only ------
__global__ void k_norm(const float* __restrict__ x, const float4* __restrict__ part,
                       const float* __restrict__ bn_w, const float* __restrict__ bn_b,
                       char* __restrict__ XNg) {
    __shared__ float4 ssl[128];
    __shared__ __align__(16) char Tsh[32768];
    int blk = blockIdx.x;        // 128 token tiles
    int b = blk >> 6, hw0 = (blk & 63) * 64;
    int tid = threadIdx.x;
    if (tid < 128) {
        float4 p0 = part[tid * 4 + 0], p1 = part[tid * 4 + 1];
        float4 p2 = part[tid * 4 + 2], p3 = part[tid * 4 + 3];
        float sr = p0.x + p1.x + p2.x + p3.x, si = p0.y + p1.y + p2.y + p3.y;
        float qr = p0.z + p1.z + p2.z + p3.z, qi = p0.w + p1.w + p2.w + p3.w;
        const float inv = 1.0f / (float)(Bn * N);
        float mr = sr * inv, mi = si * inv;
        float vr = qr * inv - mr * mr, vi = qi * inv - mi * mi;
        float scr = bn_w[tid * 2 + 0] * rsqrtf(vr + EPS);
        float sci = bn_w[tid * 2 + 1] * rsqrtf(vi + EPS);
        ssl[tid] = make_float4(scr, bn_b[tid * 2 + 0] - mr * scr,
                               sci, bn_b[tid * 2 + 1] - mi * sci);
    }
    __syncthreads();
    const float4* xin4 = (const float4*)x;
    #pragma unroll
    for (int it = 0; it < 16; ++it) {
        int idx = it * 256 + tid;        // 4096 = 128c x 32 float4 (2 tokens)
        int c = idx >> 5, h2 = (idx & 31) * 2;
        size_t gi = ((size_t)(b * Cc + c) * N + hw0 + h2) >> 1;  // float4 idx
        float4 v = xin4[gi];
        float4 s = ssl[c];
        *(bf16_t*)(Tsh + tfrag(h2, c))           = (bf16_t)(v.x * s.x + s.y);
        *(bf16_t*)(Tsh + tfrag(h2, c + 128))     = (bf16_t)(v.y * s.z + s.w);
        *(bf16_t*)(Tsh + tfrag(h2 + 1, c))       = (bf16_t)(v.z * s.x + s.y);
        *(bf16_t*)(Tsh + tfrag(h2 + 1, c + 128)) = (bf16_t)(v.w * s.z + s.w);
    }
    __syncthreads();
    #pragma unroll
    for (int it = 0; it < 8; ++it) {
        int idx = it * 256 + tid;
        *(uint4*)(XNg + (size_t)blk * 32768 + idx * 16) = *(const uint4*)(Tsh + idx * 16);
    }
}

// ---- kernel 3: QKV GEMM [8192x256]@[256x768] bf16; fp8 frag images out ----
// (r10-proven: LDS-restaged epilogue, coalesced dwordx4 stores)
__global__ __launch_bounds__(256) void k_qkv(const char* __restrict__ XNg,
        const char* __restrict__ Wg, const float* __restrict__ bt,
        char* __restrict__ Qg, char* __restrict__ Kg, char* __restrict__ Vg) {
    __shared__ __align__(16) char Xsh[32768];
    __shared__ __align__(16) char Wsh[32768];
    int mx = blockIdx.x, ny = blockIdx.y;   // 128 x 12
    int tid = threadIdx.x;
    int w = tid >> 6, lane = tid & 63, n15 = lane & 15, quad = lane >> 4;
    const char* xs = XNg + (size_t)mx * 32768;
    const char* wsp = Wg + (size_t)ny * 32768;
    #pragma unroll
    for (int i = 0; i < 8; ++i) {
        int off = (w * 8 + i) * 1024 + lane * 16;
        gl16(xs + off, Xsh + off);
        gl16(wsp + off, Wsh + off);
    }
    __syncthreads();
    f32x4 acc[4] = {};
    #pragma unroll
    for (int ks = 0; ks < 8; ++ks) {
        bf16x8 a = *(const bf16x8*)(Xsh + (ks * 4 + w) * 1024 + lane * 16);
        #pragma unroll
        for (int t = 0; t < 4; ++t) {
            bf16x8 bw = *(const bf16x8*)(Wsh + (ks * 4 + t) * 1024 + lane * 16);
            acc[t] = MFMA16(a, bw, acc[t]);
        }
    }
    int proj = ny >> 2;            // 0=Q 1=K 2=V
    int jb = (ny & 3) * 64;
    __syncthreads();               // all MFMA reads of Xsh done
    char* Osh = Xsh;               // reuse 4KB
    #pragma unroll
    for (int t = 0; t < 4; ++t) {
        float bias = bt[ny * 64 + t * 16 + n15];
        unsigned w01 = (unsigned)__builtin_amdgcn_cvt_pk_fp8_f32(
            acc[t][0] + bias, acc[t][1] + bias, 0, false);
        unsigned w23 = (unsigned)__builtin_amdgcn_cvt_pk_fp8_f32(
            acc[t][2] + bias, acc[t][3] + bias, 0, false);
        unsigned char vb[4] = {(unsigned char)(w01 & 0xff), (unsigned char)((w01 >> 8) & 0xff),
                               (unsigned char)(w23 & 0xff), (unsigned char)((w23 >> 8) & 0xff)};
        #pragma unroll
        for (int r = 0; r < 4; ++r) {
            if (proj < 2) {
                int lf  = (t >> 1) * 4 + w;
                int lif = (((2 * t + (n15 >> 3)) & 3) << 4) + quad * 4 + r;
                Osh[lf * 512 + lif * 8 + (n15 & 7)] = vb[r];
            } else {
                int key = w * 16 + quad * 4 + r;
                int lf  = (w >> 1) * 4 + t;
                int lif = (((key >> 3) & 3) << 4) + n15;
                Osh[lf * 512 + lif * 8 + (key & 7)] = vb[r];
            }
        }
    }
    __syncthreads();
    {
        int lf = tid >> 5, sub = (tid & 31) * 16;
        size_t tile = (size_t)mx;
        int gfrag = (proj < 2) ? ((jb >> 5) * 4 + lf)
                               : ((lf >> 2) * 16 + (jb >> 4) + (lf & 3));
        char* dst = (proj == 0 ? Qg : (proj == 1 ? Kg : Vg));
        *(uint4*)(dst + tile * 16384 + (size_t)gfrag * 512 + sub) =
            *(const uint4*)(Osh + tid * 16);
    }
}

// ---- kernel 4: flash attention, FIXED-MAX softmax, fp8 Q/K/V + e5m2 P.
// Round-11: r8's EXACT index math (64-key tiles -- r3/r4's NaNs are now
// traced to 32-key chunk indexing bugs + Psh overflow, NOT to the sync
// design) + double-buffered K/V with prefetch spanning the whole iteration:
//   barrier A: s_waitcnt vmcnt(0) (tile kt landed, full drain, no counting)
//   issue 8 gl16 for tile kt+1 into the other buffers
//   QK^T -> P (HW packed cvt) -> barrier B: lgkmcnt(0) only (prefetch
//   stays in flight) -> PV on buffer cur.
// Alias audit: prefetch targets buf cur^1; all reads of it were consumed by
// MFMAs before barrier A. Psh index max 4095 < 4096; K/V frag index max 31.
// LDS 68KB -> 2 blocks/CU (same residency as r8: isolates overlap effect).
// No launch_bounds reg cap (r10's (256,4) forced 14MB of scratch spills).
__global__ __launch_bounds__(256) void k_attn(const char* __restrict__ Qg,
        const char* __restrict__ Kg, const char* __restrict__ Vg,
        bf16_t* __restrict__ Opb, float* __restrict__ Lp) {
    __shared__ __align__(16) char Ksh[2 * 16384];   // K dbuf: 64 keys x 256 ch fp8
    __shared__ __align__(16) char Vsh[2 * 16384];   // V dbuf: 256 ch x 64 keys fp8
    __shared__ __align__(16) char Psh[4096];        // P: 64 rows x 64 keys e5m2
    int bid = blockIdx.x;               // 512 = grp(8 = b*4+sp) x qt(64)
    int grp = bid & 7, qt = bid >> 3;   // grp -> XCD affinity
    int sp = grp & 3, b = grp >> 2;
    int tid = threadIdx.x;
    int w = tid >> 6, lane = tid & 63, n15 = lane & 15, quad = lane >> 4;
    int r = w >> 1, h = w & 1;

    const i64_t ONES = 0x3838383838383838L;   // e4m3 1.0 in all 8 bytes

    // Q fragments: rows qt*64 + r*32 + g*16, resident (32 VGPRs)
    i64_t qf[2][8];
    const char* qb = Qg + (size_t)(b * 64 + qt) * 16384;
    #pragma unroll
    for (int g = 0; g < 2; ++g)
        #pragma unroll
        for (int ks = 0; ks < 8; ++ks)
            qf[g][ks] = *(const i64_t*)(qb + ((ks * 4 + r * 2 + g) << 9) + lane * 8);

    f32x4 o[2][8] = {};                 // 32 rows x 128 ch accumulator
    f32x4 l_[2] = {};                   // row sums via ones-channel MFMA

    size_t kbase = (size_t)(b * 64 + sp * 16) * 16384;   // split's 16 tiles
    // prologue: stage tile 0 into buffer 0 (8 gl16/thread-quarter)
    #pragma unroll
    for (int i = 0; i < 4; ++i) {
        int off = (w * 4 + i) * 1024 + lane * 16;
        gl16(Kg + kbase + off, Ksh + off);
        gl16(Vg + kbase + off, Vsh + off);
    }

    for (int kt = 0; kt < 16; ++kt) {   // 16 tiles of 64 keys (split = 1024)
        int cur = kt & 1;
        // (A) tile kt landed; all waves done reading buf cur^1 (prev PV)
        asm volatile("s_waitcnt vmcnt(0)" ::: "memory");
        __builtin_amdgcn_s_barrier();
        __builtin_amdgcn_sched_barrier(0);

        // prefetch tile kt+1 into the other buffers; stays in flight
        // across barrier B, drained at next iteration's barrier A
        if (kt < 15) {
            size_t tb = kbase + (size_t)(kt + 1) * 16384;
            char* kb = Ksh + (cur ^ 1) * 16384;
            char* vb = Vsh + (cur ^ 1) * 16384;
            #pragma unroll
            for (int i = 0; i < 4; ++i) {
                int off = (w * 4 + i) * 1024 + lane * 16;
                gl16(Kg + tb + off, kb + off);
                gl16(Vg + tb + off, vb + off);
            }
        }

        // QK^T: 32 rows x 32 keys (key half h) over 256 ch
        const char* kc = Ksh + cur * 16384;
        f32x4 s[2][2] = {};
        #pragma unroll
        for (int ks = 0; ks < 8; ++ks) {
            #pragma unroll
            for (int c = 0; c < 2; ++c) {
                i64_t kf = *(const i64_t*)(kc + ((ks * 4 + h * 2 + c) << 9) + lane * 8);
                s[0][c] = MFMA8(qf[0][ks], kf, s[0][c]);
                s[1][c] = MFMA8(qf[1][ks], kf, s[1][c]);
            }
        }
        // P' = exp2(s*SCL - PSH), e5m2 via HW packed cvt (2 vals/instr)
        #pragma unroll
        for (int g = 0; g < 2; ++g)
            #pragma unroll
            for (int c = 0; c < 2; ++c) {
                float p0 = __builtin_amdgcn_exp2f(s[g][c][0] * SCL - PSH);
                float p1 = __builtin_amdgcn_exp2f(s[g][c][1] * SCL - PSH);
                float p2 = __builtin_amdgcn_exp2f(s[g][c][2] * SCL - PSH);
                float p3 = __builtin_amdgcn_exp2f(s[g][c][3] * SCL - PSH);
                unsigned w01 = (unsigned)__builtin_amdgcn_cvt_pk_bf8_f32(p0, p1, 0, false);
                unsigned w23 = (unsigned)__builtin_amdgcn_cvt_pk_bf8_f32(p2, p3, 0, false);
                char* pb = Psh + ((h * 4 + r * 2 + g) << 9) +
                           (((c * 2 + (n15 >> 3)) * 16 + quad * 4) << 3) + (n15 & 7);
                pb[0]  = (unsigned char)(w01 & 0xff);
                pb[8]  = (unsigned char)((w01 >> 8) & 0xff);
                pb[16] = (unsigned char)(w23 & 0xff);
                pb[24] = (unsigned char)((w23 >> 8) & 0xff);
            }
        // (B) P visible; prefetch vmem stays in flight (lgkm only)
        asm volatile("s_waitcnt lgkmcnt(0)" ::: "memory");
        __builtin_amdgcn_s_barrier();
        __builtin_amdgcn_sched_barrier(0);

        // PV (bf8 x fp8): rows r*32.. x ch-half h over 64 keys; + ones -> l
        const char* vc = Vsh + cur * 16384;
        #pragma unroll
        for (int k2 = 0; k2 < 2; ++k2) {
            i64_t pa0 = *(const i64_t*)(Psh + ((k2 * 4 + r * 2 + 0) << 9) + lane * 8);
            i64_t pa1 = *(const i64_t*)(Psh + ((k2 * 4 + r * 2 + 1) << 9) + lane * 8);
            l_[0] = MFMA85(pa0, ONES, l_[0]);
            l_[1] = MFMA85(pa1, ONES, l_[1]);
            #pragma unroll
            for (int ct = 0; ct < 8; ++ct) {
                i64_t vf = *(const i64_t*)(vc + ((k2 * 16 + h * 8 + ct) << 9) + lane * 8);
                o[0][ct] = MFMA85(pa0, vf, o[0][ct]);
                o[1][ct] = MFMA85(pa1, vf, o[1][ct]);
            }
        }
    }
    // epilogue: unnormalized O (bf16, carries 2^-PSH) + l for this split
    int tok0 = b * N + qt * 64 + r * 32;
    #pragma unroll
    for (int g = 0; g < 2; ++g) {
        #pragma unroll
        for (int ct = 0; ct < 8; ++ct)
            #pragma unroll
            for (int ri = 0; ri < 4; ++ri)
                Opb[((size_t)sp * T + tok0 + g * 16 + quad * 4 + ri) * D +
                    h * 128 + ct * 16 + n15] = (bf16_t)o[g][ct][ri];
        if (h == 0 && n15 == 0) {
            #pragma unroll
            for (int ri = 0; ri < 4; ++ri)
                Lp[sp * T + tok0 + g * 16 + quad * 4 + ri] = l_[g][ri];
        }
    }
}

// ---- kernel 5: combine splits + normalize + recompute xn + residual --------
__global__ void k_comb(const bf16_t* __restrict__ Opb, const float* __restrict__ Lp,
                       const float4* __restrict__ part, const float* __restrict__ bn_w,
                       const float* __restrict__ bn_b, const float* __restrict__ x,
                       const float* __restrict__ gamma, float* __restrict__ out) {
    __shared__ float4 ssl[128];
    __shared__ float wts[16];
    __shared__ float Ot[256 * 17];
    int blk = blockIdx.x;                // 512 blocks x 16 tokens
    int b = blk >> 8, hw0 = (blk & 255) * 16;
    int tok0 = b * N + hw0;
    int tid = threadIdx.x;
    if (tid < 128) {
        float4 p0 = part[tid * 4 + 0], p1 = part[tid * 4 + 1];
        float4 p2 = part[tid * 4 + 2], p3 = part[tid * 4 + 3];
        float sr = p0.x + p1.x + p2.x + p3.x, si = p0.y + p1.y + p2.y + p3.y;
        float qr = p0.z + p1.z + p2.z + p3.z, qi = p0.w + p1.w + p2.w + p3.w;
        const float inv = 1.0f / (float)(Bn * N);
        float mr = sr * inv, mi = si * inv;
        float vr = qr * inv - mr * mr, vi = qi * inv - mi * mi;
        float scr = bn_w[tid * 2 + 0] * rsqrtf(vr + EPS);
        float sci = bn_w[tid * 2 + 1] * rsqrtf(vi + EPS);
        ssl[tid] = make_float4(scr, bn_b[tid * 2 + 0] - mr * scr,
                               sci, bn_b[tid * 2 + 1] - mi * sci);
    }
    if (tid < 16) {
        float Z = 0.f;
        #pragma unroll
        for (int s = 0; s < NSP; ++s) Z += Lp[s * T + tok0 + tid];
        wts[tid] = gamma[0] / Z;
    }
    __syncthreads();
    #pragma unroll
    for (int i = 0; i < 2; ++i) {
        int idx = i * 256 + tid;         // 512 chunks of 8 ch (16tok x 32)
        int tk = idx >> 5, chunk = idx & 31;
        size_t base = (size_t)(tok0 + tk) * D + chunk * 8;
        float acc[8] = {};
        #pragma unroll
        for (int s = 0; s < NSP; ++s) {
            bf16x8 v = *(const bf16x8*)(Opb + (size_t)s * T * D + base);
            #pragma unroll
            for (int j = 0; j < 8; ++j) acc[j] += (float)v[j];
        }
        float ww = wts[tk];
        #pragma unroll
        for (int j = 0; j < 8; ++j) Ot[(chunk * 8 + j) * 17 + tk] = acc[j] * ww;
    }
    __syncthreads();
    const float2* xin = (const float2*)x;
    float2* xo = (float2*)out;
    #pragma unroll
    for (int i = 0; i < 8; ++i) {
        int linear = i * 256 + tid;      // 2048 = 128c x 16hw
        int c = linear >> 4, hwo = linear & 15;
        size_t idx = (size_t)(b * Cc + c) * N + hw0 + hwo;
        float2 v = xin[idx];
        float4 s = ssl[c];
        float2 res;
        res.x = v.x * s.x + s.y + Ot[c * 17 + hwo];
        res.y = v.y * s.z + s.w + Ot[(128 + c) * 17 + hwo];
        xo[idx] = res;
    }
}

extern "C" void kernel_launch(void* const* d_in, const int* in_sizes, int n_in,
                              void* d_out, int out_size, void* d_ws, size_t ws_size,
                              hipStream_t stream) {
    const float* x    = (const float*)d_in[0];
    const float* bn_w = (const float*)d_in[1];
    const float* bn_b = (const float*)d_in[2];
    const float* wq   = (const float*)d_in[3];
    const float* bq   = (const float*)d_in[4];
    const float* wk   = (const float*)d_in[5];
    const float* bk   = (const float*)d_in[6];
    const float* wv   = (const float*)d_in[7];
    const float* bv   = (const float*)d_in[8];
    const float* gam  = (const float*)d_in[9];
    float* out = (float*)d_out;

    char* ws = (char*)d_ws;
    size_t off = 0;
    auto alloc = [&](size_t bytes) -> void* {
        void* p = ws + off;
        off += (bytes + 255) & ~(size_t)255;
        return p;
    };
    float4* part = (float4*)alloc(512 * sizeof(float4));
    char*   XNg  = (char*)alloc((size_t)128 * 32768);
    char*   Wg   = (char*)alloc((size_t)12 * 32768);
    float*  bt   = (float*)alloc(768 * 4);
    char*   Qg   = (char*)alloc((size_t)128 * 16384);   // fp8 images
    char*   Kg   = (char*)alloc((size_t)128 * 16384);
    char*   Vg   = (char*)alloc((size_t)128 * 16384);
    bf16_t* Opb  = (bf16_t*)alloc((size_t)NSP * T * D * 2);
    float*  Lp   = (float*)alloc((size_t)NSP * T * 4);

    k_pre<<<1280, 256, 0, stream>>>(x, part, wq, wk, wv, bq, bk, bv, Wg, bt);
    k_norm<<<128, 256, 0, stream>>>(x, part, bn_w, bn_b, XNg);
    k_qkv<<<dim3(128, 12), 256, 0, stream>>>(XNg, Wg, bt, Qg, Kg, Vg);
    k_attn<<<512, 256, 0, stream>>>(Qg, Kg, Vg, Opb, Lp);
    k_comb<<<512, 256, 0, stream>>>(Opb, Lp, part, bn_w, bn_b, x, gam, out);
}